// Round 1
// baseline (1040.768 us; speedup 1.0000x reference)
//
#include <hip/hip_runtime.h>
#include <stdint.h>
#include <stddef.h>

// Problem constants (GraphConvolution: N=8192, S=3, D_IN=D_OUT=32)
static constexpr int NN = 8192;
static constexpr int DD = 32;
static constexpr int SS = 3;

typedef __attribute__((ext_vector_type(8))) short short8;   // 8 bf16 (4 VGPRs) — MFMA A/B frag
typedef __attribute__((ext_vector_type(4))) float floatx4;  // MFMA C/D frag

__device__ __forceinline__ unsigned short f2bf(float f) {
  // round-to-nearest-even fp32 -> bf16
  unsigned int u = __float_as_uint(f);
  u += 0x7FFFu + ((u >> 16) & 1u);
  return (unsigned short)(u >> 16);
}

// Kernel 1: preT[s][n][k] = sum_i x[k][i] * W[s][i][n] + b[s][n]   (bf16, transposed)
// Transposed layout => prop_kernel's B fragments are 16B-contiguous per lane.
extern "C" __global__ void __launch_bounds__(256)
pre_kernel(const float* __restrict__ x, const float* __restrict__ W,
           const float* __restrict__ b, unsigned short* __restrict__ preT) {
  __shared__ float xs[256 * 33];   // +1 pad: conflict-free row reads
  __shared__ float Ws[DD * DD];
  __shared__ float bs[DD];
  const int t = threadIdx.x;
  const int s = blockIdx.y;
  const int kbase = blockIdx.x * 256;

  // stage x[kbase .. kbase+255][0..31] (coalesced flat copy)
  #pragma unroll
  for (int j = 0; j < 32; ++j) {
    int idx = j * 256 + t;
    xs[(idx >> 5) * 33 + (idx & 31)] = x[kbase * DD + idx];
  }
  #pragma unroll
  for (int j = 0; j < 4; ++j) Ws[j * 256 + t] = W[s * DD * DD + j * 256 + t];
  if (t < DD) bs[t] = b[s * DD + t];
  __syncthreads();

  float xr[32];
  #pragma unroll
  for (int i = 0; i < 32; ++i) xr[i] = xs[t * 33 + i];

  unsigned short* o = preT + (size_t)s * DD * NN + kbase + t;  // consecutive lanes -> consecutive k
  #pragma unroll
  for (int n = 0; n < DD; ++n) {
    float acc = bs[n];
    #pragma unroll
    for (int i = 0; i < 32; ++i) acc += xr[i] * Ws[i * DD + n];  // Ws broadcast read
    o[(size_t)n * NN] = f2bf(acc);
  }
}

// Kernel 2: out[m][n] = relu( sum_s sum_k adj[s][m][k] * pre[s][k][n] )
// One block per 16-row M-tile; 8 waves split K = S*NN interleaved; LDS reduce.
extern "C" __global__ void __launch_bounds__(512)
prop_kernel(const float* __restrict__ adj, const unsigned short* __restrict__ preT,
            float* __restrict__ out) {
  const int tid  = threadIdx.x;
  const int wave = tid >> 6;
  const int lane = tid & 63;
  const int q = lane >> 4;   // 0..3
  const int c = lane & 15;   // 0..15
  const int m0 = blockIdx.x * 16;

  // A-fragment lane base: adj[s][m0 + c][k0 + q*8 .. +7]  (8 consecutive fp32)
  const float* abase = adj + (size_t)(m0 + c) * NN + q * 8;
  // B-fragment lane base: preT[s][n0 + c][k0 + q*8 .. +7] (8 consecutive bf16)
  const unsigned short* bbase = preT + (size_t)c * NN + q * 8;

  floatx4 acc0 = {0.f, 0.f, 0.f, 0.f};  // cols 0..15
  floatx4 acc1 = {0.f, 0.f, 0.f, 0.f};  // cols 16..31

  // 768 K-steps of 32 total; wave w takes st = w, w+8, w+16, ...  (96 each)
  #pragma unroll 2
  for (int it = 0; it < 96; ++it) {
    const int st = wave + (it << 3);
    const int s  = st >> 8;            // 256 steps per support
    const int k0 = (st & 255) << 5;

    const float* ap = abase + (size_t)s * NN * NN + k0;
    floatx4 alo = *(const floatx4*)ap;
    floatx4 ahi = *(const floatx4*)(ap + 4);

    const unsigned short* bp = bbase + (size_t)s * DD * NN + k0;
    short8 b0 = *(const short8*)bp;
    short8 b1 = *(const short8*)(bp + (size_t)16 * NN);

    short8 a;
    a[0] = (short)f2bf(alo[0]); a[1] = (short)f2bf(alo[1]);
    a[2] = (short)f2bf(alo[2]); a[3] = (short)f2bf(alo[3]);
    a[4] = (short)f2bf(ahi[0]); a[5] = (short)f2bf(ahi[1]);
    a[6] = (short)f2bf(ahi[2]); a[7] = (short)f2bf(ahi[3]);

    acc0 = __builtin_amdgcn_mfma_f32_16x16x32_bf16(a, b0, acc0, 0, 0, 0);
    acc1 = __builtin_amdgcn_mfma_f32_16x16x32_bf16(a, b1, acc1, 0, 0, 0);
  }

  // Cross-wave reduction. C/D layout: row = q*4 + r, col = c (m89/m91-verified).
  __shared__ float red[8 * 512];
  #pragma unroll
  for (int r = 0; r < 4; ++r) {
    red[wave * 512 + (q * 4 + r) * 32 + c]      = acc0[r];
    red[wave * 512 + (q * 4 + r) * 32 + 16 + c] = acc1[r];
  }
  __syncthreads();

  float v = 0.f;
  #pragma unroll
  for (int w = 0; w < 8; ++w) v += red[w * 512 + tid];
  v = fmaxf(v, 0.f);
  out[(size_t)m0 * DD + tid] = v;   // tid = m_local*32 + n, fully coalesced
}

extern "C" void kernel_launch(void* const* d_in, const int* in_sizes, int n_in,
                              void* d_out, int out_size, void* d_ws, size_t ws_size,
                              hipStream_t stream) {
  const float* x   = (const float*)d_in[0];  // [8192, 32]
  const float* adj = (const float*)d_in[1];  // [3, 8192, 8192]
  const float* W   = (const float*)d_in[2];  // [3, 32, 32]
  const float* b   = (const float*)d_in[3];  // [3, 32]
  float* out = (float*)d_out;                // [8192, 32]
  unsigned short* preT = (unsigned short*)d_ws;  // [3][32][8192] bf16 = 1.5 MB

  dim3 g1(NN / 256, SS);
  pre_kernel<<<g1, 256, 0, stream>>>(x, W, b, preT);
  prop_kernel<<<NN / 16, 512, 0, stream>>>(adj, preT, out);
}

// Round 2
// 1015.180 us; speedup vs baseline: 1.0252x; 1.0252x over previous
//
#include <hip/hip_runtime.h>
#include <stdint.h>
#include <stddef.h>

// GraphConvolution: out = relu( sum_s adj[s] @ (x @ W[s] + b[s]) )
// N=8192, S=3, D_IN=D_OUT=32.  adj (805 MB fp32) dominates -> HBM-bound,
// floor ~128 us at 6.3 TB/s.  Strategy: bf16 MFMA (compute ~14 us), stream adj
// with contiguous wave loads through LDS, prefetch across a no-vm-drain barrier.

static constexpr int NN = 8192;
static constexpr int DD = 32;
static constexpr int SS = 3;
static constexpr int KB = 256;             // k-chunk staged per iteration
static constexpr int LSTR = KB + 8;        // LDS row stride (shorts): 16B-aligned, even bank spread
static constexpr int NCH = SS * NN / KB;   // 96 chunks

typedef __attribute__((ext_vector_type(8))) short short8;   // 8 bf16 = 16 B
typedef __attribute__((ext_vector_type(4))) float floatx4;  // 16 B

__device__ __forceinline__ unsigned short f2bf(float f) {
  // round-to-nearest-even fp32 -> bf16
  unsigned int u = __float_as_uint(f);
  u += 0x7FFFu + ((u >> 16) & 1u);
  return (unsigned short)(u >> 16);
}

__device__ __forceinline__ void barrier_no_vm_drain() {
  // __syncthreads() lowers with s_waitcnt vmcnt(0) before s_barrier (m97/m131),
  // draining the global prefetch queue. We only need LDS ordering: lgkmcnt(0).
  asm volatile("s_waitcnt lgkmcnt(0)\n\ts_barrier" ::: "memory");
}

// Kernel 1: preT[s][n][k] = (x @ W[s] + b[s])[k][n]  stored transposed, bf16.
extern "C" __global__ void __launch_bounds__(256)
pre_kernel(const float* __restrict__ x, const float* __restrict__ W,
           const float* __restrict__ b, unsigned short* __restrict__ preT) {
  __shared__ float xs[256 * 33];
  __shared__ float Ws[DD * DD];
  __shared__ float bs[DD];
  const int t = threadIdx.x;
  const int s = blockIdx.y;
  const int kbase = blockIdx.x * 256;

  #pragma unroll
  for (int j = 0; j < 32; ++j) {
    int idx = j * 256 + t;
    xs[(idx >> 5) * 33 + (idx & 31)] = x[kbase * DD + idx];
  }
  #pragma unroll
  for (int j = 0; j < 4; ++j) Ws[j * 256 + t] = W[s * DD * DD + j * 256 + t];
  if (t < DD) bs[t] = b[s * DD + t];
  __syncthreads();

  float xr[32];
  #pragma unroll
  for (int i = 0; i < 32; ++i) xr[i] = xs[t * 33 + i];

  unsigned short* o = preT + (size_t)s * DD * NN + kbase + t;  // lanes -> consecutive k
  #pragma unroll
  for (int n = 0; n < DD; ++n) {
    float acc = bs[n];
    #pragma unroll
    for (int i = 0; i < 32; ++i) acc += xr[i] * Ws[i * DD + n];
    o[(size_t)n * NN] = f2bf(acc);
  }
}

// Kernel 2: out[m][n] = relu( sum_s sum_k adj[s][m][k] * pre[s][k][n] )
// Block = 512 threads (8 waves), M-tile = 16 rows.  Per chunk: stage 16x256 fp32
// of adj (contiguous per-lane 32B loads) -> bf16 -> LDS; 8 waves each MFMA one
// 16x16x32 k-step.  A and B for chunk ch+1 prefetched before the barrier and
// kept in flight across it (no vmcnt drain).
extern "C" __global__ void __launch_bounds__(512, 4)
prop_kernel(const float* __restrict__ adj, const unsigned short* __restrict__ preT,
            float* __restrict__ out) {
  const int tid  = threadIdx.x;
  const int wave = tid >> 6;
  const int lane = tid & 63;
  const int q = lane >> 4;   // 0..3
  const int c = lane & 15;   // 0..15
  const int m0 = blockIdx.x * 16;

  __shared__ unsigned short As[2][16 * LSTR];  // 16.9 KB
  __shared__ float red[8 * 512];               // 16 KB

  // Staging map: thread t loads 8 consecutive floats of row (t>>5), k-off (t&31)*8.
  // Half-wave = 1 KB contiguous within one row -> fully coalesced.
  const int srow  = tid >> 5;
  const int skoff = (tid & 31) * 8;
  const float* gA = adj + (size_t)(m0 + srow) * NN + skoff;

  // B fragment base: preT[c][wave*32 + q*8 ...] (16 B contiguous per lane, L2-resident)
  const unsigned short* gB = preT + (size_t)c * NN + wave * 32 + q * 8;

  floatx4 acc0 = {0.f, 0.f, 0.f, 0.f};
  floatx4 acc1 = {0.f, 0.f, 0.f, 0.f};

  // chunk ch: support s = ch>>5, k-base kc = (ch&31)*256
  auto a_addr = [&](int ch) -> const float* {
    return gA + ((size_t)(ch >> 5) << 26) + ((ch & 31) << 8);
  };
  auto b_addr = [&](int ch) -> const unsigned short* {
    return gB + ((size_t)(ch >> 5) << 18) + ((ch & 31) << 8);
  };

  // Prologue: chunk 0 loads in flight.
  floatx4 ca0, ca1;
  short8  cb0, cb1;
  {
    const float* p = a_addr(0);
    ca0 = *(const floatx4*)p;
    ca1 = *(const floatx4*)(p + 4);
    const unsigned short* bp = b_addr(0);
    cb0 = *(const short8*)bp;
    cb1 = *(const short8*)(bp + 16 * NN);
  }

  unsigned short* const dst0 = &As[0][srow * LSTR + skoff];
  unsigned short* const dst1 = &As[1][srow * LSTR + skoff];
  const unsigned short* const af0 = &As[0][c * LSTR + wave * 32 + q * 8];
  const unsigned short* const af1 = &As[1][c * LSTR + wave * 32 + q * 8];

  #pragma unroll 2
  for (int ch = 0; ch < NCH; ++ch) {
    // Prefetch chunk ch+1 (last iter: harmless reload of chunk 95).
    const int chn = (ch + 1 < NCH) ? ch + 1 : NCH - 1;
    const float* pa = a_addr(chn);
    floatx4 na0 = *(const floatx4*)pa;
    floatx4 na1 = *(const floatx4*)(pa + 4);
    const unsigned short* pb = b_addr(chn);
    short8 nb0 = *(const short8*)pb;
    short8 nb1 = *(const short8*)(pb + 16 * NN);

    // Commit current chunk to LDS as bf16 (waits only on ca*, issued last iter).
    short8 w;
    w[0] = (short)f2bf(ca0[0]); w[1] = (short)f2bf(ca0[1]);
    w[2] = (short)f2bf(ca0[2]); w[3] = (short)f2bf(ca0[3]);
    w[4] = (short)f2bf(ca1[0]); w[5] = (short)f2bf(ca1[1]);
    w[6] = (short)f2bf(ca1[2]); w[7] = (short)f2bf(ca1[3]);
    *(short8*)((ch & 1) ? dst1 : dst0) = w;

    barrier_no_vm_drain();  // prefetch stays in flight

    // Compute this chunk: wave handles k-step kc + wave*32.
    const short8 a = *(const short8*)((ch & 1) ? af1 : af0);
    acc0 = __builtin_amdgcn_mfma_f32_16x16x32_bf16(a, cb0, acc0, 0, 0, 0);
    acc1 = __builtin_amdgcn_mfma_f32_16x16x32_bf16(a, cb1, acc1, 0, 0, 0);

    ca0 = na0; ca1 = na1; cb0 = nb0; cb1 = nb1;
  }

  // Cross-wave reduction. C/D layout: row = q*4 + r, col = c (m89/m91-verified,
  // correctness-proven in R1).
  #pragma unroll
  for (int r = 0; r < 4; ++r) {
    red[wave * 512 + (q * 4 + r) * 32 + c]      = acc0[r];
    red[wave * 512 + (q * 4 + r) * 32 + 16 + c] = acc1[r];
  }
  __syncthreads();

  float v = 0.f;
  #pragma unroll
  for (int w2 = 0; w2 < 8; ++w2) v += red[w2 * 512 + tid];
  out[(size_t)m0 * DD + tid] = fmaxf(v, 0.f);  // tid = m_local*32 + n, coalesced
}

extern "C" void kernel_launch(void* const* d_in, const int* in_sizes, int n_in,
                              void* d_out, int out_size, void* d_ws, size_t ws_size,
                              hipStream_t stream) {
  const float* x   = (const float*)d_in[0];  // [8192, 32]
  const float* adj = (const float*)d_in[1];  // [3, 8192, 8192]
  const float* W   = (const float*)d_in[2];  // [3, 32, 32]
  const float* b   = (const float*)d_in[3];  // [3, 32]
  float* out = (float*)d_out;                // [8192, 32]
  unsigned short* preT = (unsigned short*)d_ws;  // [3][32][8192] bf16 = 1.5 MB

  dim3 g1(NN / 256, SS);
  pre_kernel<<<g1, 256, 0, stream>>>(x, W, b, preT);
  prop_kernel<<<NN / 16, 512, 0, stream>>>(adj, preT, out);
}